// Round 7
// baseline (154.145 us; speedup 1.0000x reference)
//
#include <hip/hip_runtime.h>
#include <math.h>

#define N_CELLS_C 100000
#define N_ISO_C 16
#define KP1_C 31
#define BLOCK 256

typedef _Float16 hf2 __attribute__((ext_vector_type(2)));
union Rec16 { float4 f; hf2 h[4]; };

__device__ __forceinline__ float fdot2f(hf2 a, hf2 b, float c) {
    return __builtin_amdgcn_fdot2(a, b, c, false);
}

// Per-wave index-dtype detect: int64 indices (< 2^17) have all odd int32
// words == 0; int32 random indices make that astronomically unlikely.
__device__ __forceinline__ int idx_shift(const char* idx_bytes) {
    const int lane = threadIdx.x & 63;
    int probe = 0;
    if (lane < 16) probe = ((const int*)idx_bytes)[2 * lane + 1];
    return __any(probe != 0) ? 2 : 3;   // log2(bytes per index)
}

// Pack: rec[cell] = 16 x fp16 splices (32B), u16[cell] = fp16 unsplice.
// Also resets the cross-block accumulator/counter used by cost_kernel_h
// (stream order guarantees this completes before cost_kernel_h starts).
__global__ __launch_bounds__(BLOCK) void pack_kernel(
    const float* __restrict__ unsplice,
    const float* __restrict__ splices,
    char* __restrict__ rec,
    _Float16* __restrict__ u16,
    float* __restrict__ accum,
    int* __restrict__ counter)
{
    const int t = blockIdx.x * BLOCK + threadIdx.x;
    if (t == 0) { *accum = 0.0f; *counter = 0; }
    const int cell = t >> 1, h = t & 1;
    if (cell >= N_CELLS_C) return;
    const float* srow = splices + (long long)cell * N_ISO_C + 8 * h;
    const float4 a = *(const float4*)srow;
    const float4 b = *(const float4*)(srow + 4);
    Rec16 r;
    r.h[0] = hf2{(_Float16)a.x, (_Float16)a.y};
    r.h[1] = hf2{(_Float16)a.z, (_Float16)a.w};
    r.h[2] = hf2{(_Float16)b.x, (_Float16)b.y};
    r.h[3] = hf2{(_Float16)b.z, (_Float16)b.w};
    *(float4*)(rec + ((long long)cell << 5) + (h << 4)) = r.f;
    if (h == 0) u16[cell] = (_Float16)unsplice[cell];
}

// 8 lanes/cell: pair h = sub>>1 handles neighbors k = 1+h+4t; lane w = sub&1
// owns the 16B half of the 32B record. All 8 records + u16 explicitly
// preloaded -> 16 independent loads in flight per lane.
__global__ __launch_bounds__(BLOCK) void cost_kernel_h(
    const float* __restrict__ unsplice,
    const float* __restrict__ splices,
    const float* __restrict__ unsplice_predict,
    const float* __restrict__ splice_predicts,
    const char*  __restrict__ idx_bytes,
    const char*  __restrict__ rec,
    const _Float16* __restrict__ u16,
    float*       __restrict__ accum,
    int*         __restrict__ counter,
    float*       __restrict__ out,
    int          nblocks)
{
    const int tid  = threadIdx.x;
    const int sub  = tid & 7;
    const int w    = sub & 1;
    const int h    = sub >> 1;
    const int cell = blockIdx.x * (BLOCK / 8) + (tid >> 3);   // grid exact
    const int shift = idx_shift(idx_bytes);

    // Own-cell half in fp16 (same rounding as pack_kernel).
    const float* srow = splices         + (long long)cell * N_ISO_C + 8 * w;
    const float* prow = splice_predicts + (long long)cell * N_ISO_C + 8 * w;
    const float4 a  = *(const float4*)srow,  b  = *(const float4*)(srow + 4);
    const float4 pa = *(const float4*)prow,  pb = *(const float4*)(prow + 4);
    const hf2 c0{(_Float16)a.x,  (_Float16)a.y},  c1{(_Float16)a.z,  (_Float16)a.w};
    const hf2 c2{(_Float16)b.x,  (_Float16)b.y},  c3{(_Float16)b.z,  (_Float16)b.w};
    const hf2 q0{(_Float16)pa.x, (_Float16)pa.y}, q1{(_Float16)pa.z, (_Float16)pa.w};
    const hf2 q2{(_Float16)pb.x, (_Float16)pb.y}, q3{(_Float16)pb.z, (_Float16)pb.w};
    const hf2 v0 = q0 - c0, v1 = q1 - c1, v2 = q2 - c2, v3 = q3 - c3;

    const float u_i = (float)(_Float16)unsplice[cell];
    const float uv  = unsplice_predict[cell] - unsplice[cell];

    float vp = fdot2f(v0, v0, fdot2f(v1, v1, fdot2f(v2, v2, fdot2f(v3, v3, 0.f))));
    vp += __shfl_xor(vp, 1);
    const float vn2 = vp + uv * uv;
    const float inv_vi = (vn2 > 0.f) ? rsqrtf(vn2) : 0.f;   // zero-norm -> cost 1 (ref: denom->1, dot 0)

    const long long base = (long long)cell * KP1_C;
    int jv[8];
    #pragma unroll
    for (int t = 0; t < 8; ++t) {
        int k = 1 + h + 4 * t;
        if (k > 30) k = 30;                                  // duplicate (safe under max)
        jv[t] = *(const int*)(idx_bytes + ((base + k) << shift));
    }

    // Explicit preload: 8 record halves + 8 u16 -> 16 loads in flight.
    Rec16 g[8];
    _Float16 ujh[8];
    #pragma unroll
    for (int t = 0; t < 8; ++t) {
        g[t] = *(const Rec16*)(rec + ((long long)jv[t] << 5) + (w << 4));
        ujh[t] = u16[jv[t]];
    }

    float maxq = -INFINITY;
    #pragma unroll
    for (int t = 0; t < 8; ++t) {
        const hf2 d0 = g[t].h[0] - c0;
        const hf2 d1 = g[t].h[1] - c1;
        const hf2 d2 = g[t].h[2] - c2;
        const hf2 d3 = g[t].h[3] - c3;
        float dp = fdot2f(v0, d0, fdot2f(v1, d1, fdot2f(v2, d2, fdot2f(v3, d3, 0.f))));
        float np = fdot2f(d0, d0, fdot2f(d1, d1, fdot2f(d2, d2, fdot2f(d3, d3, 0.f))));
        dp += __shfl_xor(dp, 1);
        np += __shfl_xor(np, 1);
        const float un  = (float)ujh[t] - u_i;
        const float dot = dp + uv * un;
        const float nn2 = np + un * un;
        const float rn  = (nn2 > 0.f) ? rsqrtf(nn2) : 0.f;
        maxq = fmaxf(maxq, dot * rn);
    }
    maxq = fmaxf(maxq, __shfl_xor(maxq, 2));
    maxq = fmaxf(maxq, __shfl_xor(maxq, 4));

    float cost = (sub == 0) ? (1.0f - maxq * inv_vi) : 0.f;

    for (int off = 32; off > 0; off >>= 1) cost += __shfl_down(cost, off);
    __shared__ float wsum[BLOCK / 64];
    if ((tid & 63) == 0) wsum[tid >> 6] = cost;
    __syncthreads();
    if (tid == 0) {
        float s = 0.f;
        #pragma unroll
        for (int wv = 0; wv < BLOCK / 64; ++wv) s += wsum[wv];
        // Fused final reduce: device-scope atomics (XCD-coherence safe).
        atomicAdd(accum, s);
        __threadfence();                       // accum-add visible before counter-add
        const int old = atomicAdd(counter, 1);
        if (old == nblocks - 1) {
            __threadfence();
            const float tot = atomicAdd(accum, 0.0f);   // coherent read
            out[0] = tot / (float)N_CELLS_C;
        }
    }
}

// -------- fp32 fallback (used only if ws_size is too small) -------
__global__ __launch_bounds__(BLOCK) void cost_kernel_f32(
    const float* __restrict__ unsplice,
    const float* __restrict__ splices,
    const float* __restrict__ unsplice_predict,
    const float* __restrict__ splice_predicts,
    const char*  __restrict__ idx_bytes,
    float*       __restrict__ partials)
{
    const int tid  = threadIdx.x;
    const int q    = tid & 3;
    const int cell = blockIdx.x * (BLOCK / 4) + (tid >> 2);
    const int shift = idx_shift(idx_bytes);

    float cost = 0.0f;
    if (cell < N_CELLS_C) {
        const float u_i = unsplice[cell];
        const float uv  = unsplice_predict[cell] - u_i;
        const float4 s4  = *(const float4*)(splices         + (long long)cell * N_ISO_C + 4 * q);
        const float4 sp4 = *(const float4*)(splice_predicts + (long long)cell * N_ISO_C + 4 * q);
        const float v0 = sp4.x - s4.x, v1 = sp4.y - s4.y, v2 = sp4.z - s4.z, v3 = sp4.w - s4.w;
        float vpp = v0*v0 + v1*v1 + v2*v2 + v3*v3;
        vpp += __shfl_xor(vpp, 1);
        vpp += __shfl_xor(vpp, 2);
        const float vn2 = vpp + uv * uv;
        const float inv_vi = (vn2 > 0.0f) ? rsqrtf(vn2) : 0.0f;
        const long long base = (long long)cell * KP1_C;
        float maxq = -INFINITY;
        #pragma unroll
        for (int k = 1; k < KP1_C; ++k) {
            const int j = *(const int*)(idx_bytes + ((base + k) << shift));
            const float unj = unsplice[j];
            const float4 n4 = *(const float4*)(splices + (long long)j * N_ISO_C + 4 * q);
            const float d0 = n4.x - s4.x, d1 = n4.y - s4.y, d2 = n4.z - s4.z, d3 = n4.w - s4.w;
            float dp = v0*d0 + v1*d1 + v2*d2 + v3*d3;
            float np = d0*d0 + d1*d1 + d2*d2 + d3*d3;
            dp += __shfl_xor(dp, 1);  np += __shfl_xor(np, 1);
            dp += __shfl_xor(dp, 2);  np += __shfl_xor(np, 2);
            const float un  = unj - u_i;
            const float dot = dp + uv * un;
            const float nn2 = np + un * un;
            const float rn  = (nn2 > 0.0f) ? rsqrtf(nn2) : 0.0f;
            maxq = fmaxf(maxq, dot * rn);
        }
        if (q == 0) cost = 1.0f - maxq * inv_vi;
    }
    for (int off = 32; off > 0; off >>= 1) cost += __shfl_down(cost, off);
    __shared__ float wsum[BLOCK / 64];
    if ((tid & 63) == 0) wsum[tid >> 6] = cost;
    __syncthreads();
    if (tid == 0) {
        float s = 0.0f;
        #pragma unroll
        for (int wv = 0; wv < BLOCK / 64; ++wv) s += wsum[wv];
        partials[blockIdx.x] = s;
    }
}

__global__ __launch_bounds__(BLOCK) void final_reduce_kernel(
    const float* __restrict__ partials, int nparts, float* __restrict__ out)
{
    float s = 0.0f;
    for (int i = threadIdx.x; i < nparts; i += BLOCK) s += partials[i];
    for (int off = 32; off > 0; off >>= 1) s += __shfl_down(s, off);
    __shared__ float wsum[BLOCK / 64];
    if ((threadIdx.x & 63) == 0) wsum[threadIdx.x >> 6] = s;
    __syncthreads();
    if (threadIdx.x == 0) {
        float t = 0.0f;
        #pragma unroll
        for (int wv = 0; wv < BLOCK / 64; ++wv) t += wsum[wv];
        out[0] = t / (float)N_CELLS_C;
    }
}

extern "C" void kernel_launch(void* const* d_in, const int* in_sizes, int n_in,
                              void* d_out, int out_size, void* d_ws, size_t ws_size,
                              hipStream_t stream) {
    const float* unsplice         = (const float*)d_in[0];
    const float* splices          = (const float*)d_in[1];
    const float* unsplice_predict = (const float*)d_in[2];
    const float* splice_predicts  = (const float*)d_in[3];
    const char*  idx_bytes        = (const char*)d_in[4];
    float* out = (float*)d_out;

    // ws layout: [rec 3.2MB][u16 0.2MB][accum][counter]
    char*      rec     = (char*)d_ws;
    _Float16*  u16     = (_Float16*)((char*)d_ws + (size_t)N_CELLS_C * 32);
    float*     accum   = (float*)((char*)d_ws + 3400000);
    int*       counter = (int*)((char*)d_ws + 3400064);

    const size_t req = 3400128;

    if (ws_size >= req) {
        const int pack_blocks = (2 * N_CELLS_C + BLOCK - 1) / BLOCK;
        pack_kernel<<<pack_blocks, BLOCK, 0, stream>>>(unsplice, splices, rec, u16, accum, counter);
        const int nblocks = N_CELLS_C / (BLOCK / 8);   // 3125, exact
        cost_kernel_h<<<nblocks, BLOCK, 0, stream>>>(
            unsplice, splices, unsplice_predict, splice_predicts,
            idx_bytes, rec, u16, accum, counter, out, nblocks);
    } else {
        float* fb_partials = (float*)d_ws;
        const int nblocks = (N_CELLS_C + (BLOCK / 4) - 1) / (BLOCK / 4);
        cost_kernel_f32<<<nblocks, BLOCK, 0, stream>>>(
            unsplice, splices, unsplice_predict, splice_predicts,
            idx_bytes, fb_partials);
        final_reduce_kernel<<<1, BLOCK, 0, stream>>>(fb_partials, nblocks, out);
    }
}

// Round 8
// 41.149 us; speedup vs baseline: 3.7460x; 3.7460x over previous
//
#include <hip/hip_runtime.h>
#include <math.h>

#define N_CELLS_C 100000
#define N_ISO_C 16
#define KP1_C 31
#define BLOCK 256
#define CPB 64   // cells per block in cost kernel (4 lanes/cell)

// Per-wave index-dtype detect: int64 indices (< 2^17) have all odd int32
// words == 0; int32 random indices make that astronomically unlikely.
__device__ __forceinline__ int idx_shift(const char* idx_bytes) {
    const int lane = threadIdx.x & 63;
    int probe = 0;
    if (lane < 16) probe = ((const int*)idx_bytes)[2 * lane + 1];
    return __any(probe != 0) ? 2 : 3;   // log2(bytes per index)
}

// 14-bit float = fp16 with low 2 mantissa bits dropped (round-to-nearest).
// rel err <= 2^-9. 17 values * 14b = 238b -> one 32B record (1 line/neighbor).
__device__ __forceinline__ unsigned enc14(float x) {
    const _Float16 h = (_Float16)x;
    const unsigned short b = __builtin_bit_cast(unsigned short, h);
    return (((unsigned)b + 2u) >> 2) & 0x3FFFu;
}
__device__ __forceinline__ float dec14(unsigned v) {
    const unsigned short b = (unsigned short)(v << 2);
    const _Float16 h = __builtin_bit_cast(_Float16, b);
    return (float)h;
}

// One thread per cell: encode [s0..s15, u] into 8 u32 (32B record).
__global__ __launch_bounds__(BLOCK) void pack_kernel(
    const float* __restrict__ unsplice,
    const float* __restrict__ splices,
    unsigned* __restrict__ rec)
{
    const int cell = blockIdx.x * BLOCK + threadIdx.x;
    if (cell >= N_CELLS_C) return;
    const float4* row = (const float4*)(splices + (long long)cell * N_ISO_C);
    const float4 r0 = row[0], r1 = row[1], r2 = row[2], r3 = row[3];
    float vals[17] = { r0.x, r0.y, r0.z, r0.w, r1.x, r1.y, r1.z, r1.w,
                       r2.x, r2.y, r2.z, r2.w, r3.x, r3.y, r3.z, r3.w,
                       unsplice[cell] };
    unsigned w[8] = {0, 0, 0, 0, 0, 0, 0, 0};
    #pragma unroll
    for (int i = 0; i < 17; ++i) {
        const unsigned v = enc14(vals[i]);
        const int s = 14 * i, k = s >> 5, off = s & 31;
        w[k] |= v << off;
        if (off > 18) w[k + 1] |= v >> (32 - off);
    }
    uint4* dst = (uint4*)(rec + (size_t)cell * 8);
    dst[0] = uint4{w[0], w[1], w[2], w[3]};
    dst[1] = uint4{w[4], w[5], w[6], w[7]};
}

// 4 lanes/cell; lane q handles neighbors k = 1+q+4t (t=0..7, clamped).
// Full 17-dim center in fp32 registers; neighbor = one 32B record decode.
__global__ __launch_bounds__(BLOCK) void cost_kernel(
    const float* __restrict__ unsplice,
    const float* __restrict__ splices,
    const float* __restrict__ unsplice_predict,
    const float* __restrict__ splice_predicts,
    const char*  __restrict__ idx_bytes,
    const unsigned* __restrict__ rec,
    float*       __restrict__ partials)
{
    const int tid  = threadIdx.x;
    const int q    = tid & 3;
    const int cell = blockIdx.x * CPB + (tid >> 2);
    const int shift = idx_shift(idx_bytes);

    float cost = 0.0f;
    if (cell < N_CELLS_C) {
        // center (exact fp32): ci[0..15]=splices row, ci[16]=unsplice
        float ci[17], v[17];
        {
            const float4* sr = (const float4*)(splices         + (long long)cell * N_ISO_C);
            const float4* pr = (const float4*)(splice_predicts + (long long)cell * N_ISO_C);
            #pragma unroll
            for (int b = 0; b < 4; ++b) {
                const float4 s4 = sr[b], p4 = pr[b];
                ci[4*b+0] = s4.x; ci[4*b+1] = s4.y; ci[4*b+2] = s4.z; ci[4*b+3] = s4.w;
                v[4*b+0] = p4.x - s4.x; v[4*b+1] = p4.y - s4.y;
                v[4*b+2] = p4.z - s4.z; v[4*b+3] = p4.w - s4.w;
            }
            ci[16] = unsplice[cell];
            v[16]  = unsplice_predict[cell] - ci[16];
        }
        float vn2 = 0.f;
        #pragma unroll
        for (int i = 0; i < 17; ++i) vn2 = fmaf(v[i], v[i], vn2);
        // max_k (dot_k * rsqrt(nn2_k)) * (1/|v|): positive scale commutes with
        // max; zero norms force contribution 0 (ref: denom==0 -> 1, dot==0).
        const float inv_vi = (vn2 > 0.f) ? rsqrtf(vn2) : 0.f;

        const long long base = (long long)cell * KP1_C;
        int jv[8];
        #pragma unroll
        for (int t = 0; t < 8; ++t) {
            int k = 1 + q + 4 * t;
            if (k > 30) k = 30;                    // duplicate (safe under max)
            jv[t] = *(const int*)(idx_bytes + ((base + k) << shift));
        }

        float maxq = -INFINITY;
        #pragma unroll
        for (int c2 = 0; c2 < 2; ++c2) {
            uint4 ga[4], gb[4];
            #pragma unroll
            for (int t = 0; t < 4; ++t) {          // 4 record loads in flight
                const uint4* p = (const uint4*)(rec + (size_t)jv[c2 * 4 + t] * 8);
                ga[t] = p[0];
                gb[t] = p[1];
            }
            #pragma unroll
            for (int t = 0; t < 4; ++t) {
                const unsigned w[8] = { ga[t].x, ga[t].y, ga[t].z, ga[t].w,
                                        gb[t].x, gb[t].y, gb[t].z, gb[t].w };
                float dot = 0.f, nn2 = 0.f;
                #pragma unroll
                for (int i = 0; i < 17; ++i) {
                    const int s = 14 * i, k = s >> 5, off = s & 31;
                    unsigned raw = w[k] >> off;
                    if (off > 18) raw |= w[k + 1] << (32 - off);
                    const float g = dec14(raw & 0x3FFFu);
                    const float d = g - ci[i];
                    dot = fmaf(v[i], d, dot);
                    nn2 = fmaf(d, d, nn2);
                }
                const float rn = (nn2 > 0.f) ? rsqrtf(nn2) : 0.f;
                maxq = fmaxf(maxq, dot * rn);
            }
        }
        maxq = fmaxf(maxq, __shfl_xor(maxq, 1));
        maxq = fmaxf(maxq, __shfl_xor(maxq, 2));
        if (q == 0) cost = 1.0f - maxq * inv_vi;
    }

    // block tree-sum (deterministic), partials + separate final reduce (NO atomics)
    for (int off = 32; off > 0; off >>= 1) cost += __shfl_down(cost, off);
    __shared__ float wsum[BLOCK / 64];
    if ((tid & 63) == 0) wsum[tid >> 6] = cost;
    __syncthreads();
    if (tid == 0) {
        float s = 0.f;
        #pragma unroll
        for (int wv = 0; wv < BLOCK / 64; ++wv) s += wsum[wv];
        partials[blockIdx.x] = s;
    }
}

// -------- fp32 fallback (used only if ws_size is too small) -------
__global__ __launch_bounds__(BLOCK) void cost_kernel_f32(
    const float* __restrict__ unsplice,
    const float* __restrict__ splices,
    const float* __restrict__ unsplice_predict,
    const float* __restrict__ splice_predicts,
    const char*  __restrict__ idx_bytes,
    float*       __restrict__ partials)
{
    const int tid  = threadIdx.x;
    const int q    = tid & 3;
    const int cell = blockIdx.x * (BLOCK / 4) + (tid >> 2);
    const int shift = idx_shift(idx_bytes);

    float cost = 0.0f;
    if (cell < N_CELLS_C) {
        const float u_i = unsplice[cell];
        const float uv  = unsplice_predict[cell] - u_i;
        const float4 s4  = *(const float4*)(splices         + (long long)cell * N_ISO_C + 4 * q);
        const float4 sp4 = *(const float4*)(splice_predicts + (long long)cell * N_ISO_C + 4 * q);
        const float v0 = sp4.x - s4.x, v1 = sp4.y - s4.y, v2 = sp4.z - s4.z, v3 = sp4.w - s4.w;
        float vpp = v0*v0 + v1*v1 + v2*v2 + v3*v3;
        vpp += __shfl_xor(vpp, 1);
        vpp += __shfl_xor(vpp, 2);
        const float vn2 = vpp + uv * uv;
        const float inv_vi = (vn2 > 0.0f) ? rsqrtf(vn2) : 0.0f;
        const long long base = (long long)cell * KP1_C;
        float maxq = -INFINITY;
        #pragma unroll
        for (int k = 1; k < KP1_C; ++k) {
            const int j = *(const int*)(idx_bytes + ((base + k) << shift));
            const float unj = unsplice[j];
            const float4 n4 = *(const float4*)(splices + (long long)j * N_ISO_C + 4 * q);
            const float d0 = n4.x - s4.x, d1 = n4.y - s4.y, d2 = n4.z - s4.z, d3 = n4.w - s4.w;
            float dp = v0*d0 + v1*d1 + v2*d2 + v3*d3;
            float np = d0*d0 + d1*d1 + d2*d2 + d3*d3;
            dp += __shfl_xor(dp, 1);  np += __shfl_xor(np, 1);
            dp += __shfl_xor(dp, 2);  np += __shfl_xor(np, 2);
            const float un  = unj - u_i;
            const float dot = dp + uv * un;
            const float nn2 = np + un * un;
            const float rn  = (nn2 > 0.0f) ? rsqrtf(nn2) : 0.0f;
            maxq = fmaxf(maxq, dot * rn);
        }
        if (q == 0) cost = 1.0f - maxq * inv_vi;
    }
    for (int off = 32; off > 0; off >>= 1) cost += __shfl_down(cost, off);
    __shared__ float wsum[BLOCK / 64];
    if ((tid & 63) == 0) wsum[tid >> 6] = cost;
    __syncthreads();
    if (tid == 0) {
        float s = 0.0f;
        #pragma unroll
        for (int wv = 0; wv < BLOCK / 64; ++wv) s += wsum[wv];
        partials[blockIdx.x] = s;
    }
}

__global__ __launch_bounds__(BLOCK) void final_reduce_kernel(
    const float* __restrict__ partials, int nparts, float* __restrict__ out)
{
    float s = 0.0f;
    for (int i = threadIdx.x; i < nparts; i += BLOCK) s += partials[i];
    for (int off = 32; off > 0; off >>= 1) s += __shfl_down(s, off);
    __shared__ float wsum[BLOCK / 64];
    if ((threadIdx.x & 63) == 0) wsum[threadIdx.x >> 6] = s;
    __syncthreads();
    if (threadIdx.x == 0) {
        float t = 0.0f;
        #pragma unroll
        for (int wv = 0; wv < BLOCK / 64; ++wv) t += wsum[wv];
        out[0] = t / (float)N_CELLS_C;
    }
}

extern "C" void kernel_launch(void* const* d_in, const int* in_sizes, int n_in,
                              void* d_out, int out_size, void* d_ws, size_t ws_size,
                              hipStream_t stream) {
    const float* unsplice         = (const float*)d_in[0];
    const float* splices          = (const float*)d_in[1];
    const float* unsplice_predict = (const float*)d_in[2];
    const float* splice_predicts  = (const float*)d_in[3];
    const char*  idx_bytes        = (const char*)d_in[4];
    float* out = (float*)d_out;

    // ws layout: [rec 3.2MB][partials]
    unsigned* rec      = (unsigned*)d_ws;
    float*    partials = (float*)((char*)d_ws + 3200000);

    const size_t req = 3200000 + 8 * 4096;

    if (ws_size >= req) {
        const int pack_blocks = (N_CELLS_C + BLOCK - 1) / BLOCK;      // 391
        pack_kernel<<<pack_blocks, BLOCK, 0, stream>>>(unsplice, splices, rec);
        const int nblocks = (N_CELLS_C + CPB - 1) / CPB;              // 1563
        cost_kernel<<<nblocks, BLOCK, 0, stream>>>(
            unsplice, splices, unsplice_predict, splice_predicts,
            idx_bytes, rec, partials);
        final_reduce_kernel<<<1, BLOCK, 0, stream>>>(partials, nblocks, out);
    } else {
        float* fb_partials = (float*)d_ws;
        const int nblocks = (N_CELLS_C + (BLOCK / 4) - 1) / (BLOCK / 4);
        cost_kernel_f32<<<nblocks, BLOCK, 0, stream>>>(
            unsplice, splices, unsplice_predict, splice_predicts,
            idx_bytes, fb_partials);
        final_reduce_kernel<<<1, BLOCK, 0, stream>>>(fb_partials, nblocks, out);
    }
}

// Round 9
// 39.140 us; speedup vs baseline: 3.9383x; 1.0513x over previous
//
#include <hip/hip_runtime.h>
#include <math.h>

#define N_CELLS_C 100000
#define N_ISO_C 16
#define KP1_C 31
#define BLOCK 256

// Per-wave index-dtype detect: int64 indices (< 2^17) have all odd int32
// words == 0; int32 random indices make that astronomically unlikely.
__device__ __forceinline__ int idx_shift(const char* idx_bytes) {
    const int lane = threadIdx.x & 63;
    int probe = 0;
    if (lane < 16) probe = ((const int*)idx_bytes)[2 * lane + 1];
    return __any(probe != 0) ? 2 : 3;   // log2(bytes per index)
}

// 14-bit float = fp16 with low 2 mantissa bits dropped (round-to-nearest).
__device__ __forceinline__ unsigned enc14(float x) {
    const _Float16 h = (_Float16)x;
    const unsigned short b = __builtin_bit_cast(unsigned short, h);
    return (((unsigned)b + 2u) >> 2) & 0x3FFFu;
}
__device__ __forceinline__ float dec14(unsigned v) {
    const unsigned short b = (unsigned short)(v << 2);
    const _Float16 h = __builtin_bit_cast(_Float16, b);
    return (float)h;
}

// Record: 32B, two INDEPENDENT 16B halves.
//   half0 (words 0-3): dims 0..8   (9 x 14b = 126b)
//   half1 (words 4-7): dims 9..15, u  (8 x 14b = 112b; slot 8 zero)
__global__ __launch_bounds__(BLOCK) void pack_kernel(
    const float* __restrict__ unsplice,
    const float* __restrict__ splices,
    unsigned* __restrict__ rec)
{
    const int cell = blockIdx.x * BLOCK + threadIdx.x;
    if (cell >= N_CELLS_C) return;
    const float4* row = (const float4*)(splices + (long long)cell * N_ISO_C);
    const float4 r0 = row[0], r1 = row[1], r2 = row[2], r3 = row[3];
    const float h0[9] = { r0.x, r0.y, r0.z, r0.w, r1.x, r1.y, r1.z, r1.w, r2.x };
    const float h1[8] = { r2.y, r2.z, r2.w, r3.x, r3.y, r3.z, r3.w, unsplice[cell] };
    unsigned w[8] = {0,0,0,0,0,0,0,0};
    #pragma unroll
    for (int i = 0; i < 9; ++i) {
        const unsigned v = enc14(h0[i]);
        const int s = 14 * i, k = s >> 5, off = s & 31;
        w[k] |= v << off;
        if (off > 18) w[k + 1] |= v >> (32 - off);
    }
    #pragma unroll
    for (int i = 0; i < 8; ++i) {
        const unsigned v = enc14(h1[i]);
        const int s = 14 * i, k = 4 + (s >> 5), off = s & 31;
        w[k] |= v << off;
        if (off > 18) w[k + 1] |= v >> (32 - off);
    }
    uint4* dst = (uint4*)(rec + (size_t)cell * 8);
    dst[0] = uint4{w[0], w[1], w[2], w[3]};
    dst[1] = uint4{w[4], w[5], w[6], w[7]};
}

// 8 lanes/cell = 4 pairs. Pair p owns neighbors k = 1+p+4t (t=0..7, clamped);
// lane w of the pair loads/decodes the 16B half w. Per-lane state ~9 dims ->
// low VGPR -> 8 waves/SIMD for latency hiding. Slot 8 of half1 decodes to 0
// and ci/v are 0 there, so it contributes nothing (branch-free).
__global__ __launch_bounds__(BLOCK, 8) void cost_kernel(
    const float* __restrict__ unsplice,
    const float* __restrict__ splices,
    const float* __restrict__ unsplice_predict,
    const float* __restrict__ splice_predicts,
    const char*  __restrict__ idx_bytes,
    const unsigned* __restrict__ rec,
    float*       __restrict__ partials)
{
    const int tid  = threadIdx.x;
    const int sub  = tid & 7;
    const int w    = sub & 1;
    const int p    = sub >> 1;
    const int cell = blockIdx.x * (BLOCK / 8) + (tid >> 3);   // grid exact: 3125*32
    const int shift = idx_shift(idx_bytes);

    // Center half in fp32 (exact), 9 slots; half1 slot 8 = 0.
    float ci[9], v[9];
    {
        const float4* sr = (const float4*)(splices         + (long long)cell * N_ISO_C);
        const float4* pr = (const float4*)(splice_predicts + (long long)cell * N_ISO_C);
        if (w == 0) {
            const float4 a = sr[0], b = sr[1]; const float c2 = sr[2].x;
            const float4 pa = pr[0], pb = pr[1]; const float pc2 = pr[2].x;
            ci[0]=a.x; ci[1]=a.y; ci[2]=a.z; ci[3]=a.w;
            ci[4]=b.x; ci[5]=b.y; ci[6]=b.z; ci[7]=b.w; ci[8]=c2;
            v[0]=pa.x-a.x; v[1]=pa.y-a.y; v[2]=pa.z-a.z; v[3]=pa.w-a.w;
            v[4]=pb.x-b.x; v[5]=pb.y-b.y; v[6]=pb.z-b.z; v[7]=pb.w-b.w; v[8]=pc2-c2;
        } else {
            const float4 a = sr[2], b = sr[3];
            const float4 pa = pr[2], pb = pr[3];
            const float u  = unsplice[cell], up = unsplice_predict[cell];
            ci[0]=a.y; ci[1]=a.z; ci[2]=a.w;
            ci[3]=b.x; ci[4]=b.y; ci[5]=b.z; ci[6]=b.w; ci[7]=u; ci[8]=0.f;
            v[0]=pa.y-a.y; v[1]=pa.z-a.z; v[2]=pa.w-a.w;
            v[3]=pb.x-b.x; v[4]=pb.y-b.y; v[5]=pb.z-b.z; v[6]=pb.w-b.w;
            v[7]=up-u; v[8]=0.f;
        }
    }
    float vp = 0.f;
    #pragma unroll
    for (int i = 0; i < 9; ++i) vp = fmaf(v[i], v[i], vp);
    vp += __shfl_xor(vp, 1);
    const float inv_vi = (vp > 0.f) ? rsqrtf(vp) : 0.f;   // zero-norm -> contribution 0 (ref: denom->1, dot 0)

    const long long base = (long long)cell * KP1_C;
    int jv[8];
    #pragma unroll
    for (int t = 0; t < 8; ++t) {
        int k = 1 + p + 4 * t;
        if (k > 30) k = 30;                    // duplicate (safe under max)
        jv[t] = *(const int*)(idx_bytes + ((base + k) << shift));
    }

    float maxq = -INFINITY;
    #pragma unroll
    for (int c2 = 0; c2 < 2; ++c2) {
        uint4 G[4];
        #pragma unroll
        for (int t = 0; t < 4; ++t)            // 4 half-record loads in flight
            G[t] = *(const uint4*)(rec + (size_t)jv[c2 * 4 + t] * 8 + 4 * w);
        #pragma unroll
        for (int t = 0; t < 4; ++t) {
            const unsigned wd[4] = { G[t].x, G[t].y, G[t].z, G[t].w };
            float dp = 0.f, np = 0.f;
            #pragma unroll
            for (int i = 0; i < 9; ++i) {
                const int s = 14 * i, k = s >> 5, off = s & 31;
                unsigned raw = wd[k] >> off;
                if (off > 18) raw |= wd[k + 1] << (32 - off);
                const float g = dec14(raw & 0x3FFFu);
                const float d = g - ci[i];
                dp = fmaf(v[i], d, dp);
                np = fmaf(d, d, np);
            }
            dp += __shfl_xor(dp, 1);
            np += __shfl_xor(np, 1);
            const float rn = (np > 0.f) ? rsqrtf(np) : 0.f;
            maxq = fmaxf(maxq, dp * rn);
        }
    }
    maxq = fmaxf(maxq, __shfl_xor(maxq, 2));
    maxq = fmaxf(maxq, __shfl_xor(maxq, 4));
    float cost = (sub == 0) ? (1.0f - maxq * inv_vi) : 0.f;

    // block tree-sum (deterministic) -> partials; separate final reduce (no atomics)
    for (int off = 32; off > 0; off >>= 1) cost += __shfl_down(cost, off);
    __shared__ float wsum[BLOCK / 64];
    if ((tid & 63) == 0) wsum[tid >> 6] = cost;
    __syncthreads();
    if (tid == 0) {
        float s = 0.f;
        #pragma unroll
        for (int wv = 0; wv < BLOCK / 64; ++wv) s += wsum[wv];
        partials[blockIdx.x] = s;
    }
}

// -------- fp32 fallback (used only if ws_size is too small) -------
__global__ __launch_bounds__(BLOCK) void cost_kernel_f32(
    const float* __restrict__ unsplice,
    const float* __restrict__ splices,
    const float* __restrict__ unsplice_predict,
    const float* __restrict__ splice_predicts,
    const char*  __restrict__ idx_bytes,
    float*       __restrict__ partials)
{
    const int tid  = threadIdx.x;
    const int q    = tid & 3;
    const int cell = blockIdx.x * (BLOCK / 4) + (tid >> 2);
    const int shift = idx_shift(idx_bytes);

    float cost = 0.0f;
    if (cell < N_CELLS_C) {
        const float u_i = unsplice[cell];
        const float uv  = unsplice_predict[cell] - u_i;
        const float4 s4  = *(const float4*)(splices         + (long long)cell * N_ISO_C + 4 * q);
        const float4 sp4 = *(const float4*)(splice_predicts + (long long)cell * N_ISO_C + 4 * q);
        const float v0 = sp4.x - s4.x, v1 = sp4.y - s4.y, v2 = sp4.z - s4.z, v3 = sp4.w - s4.w;
        float vpp = v0*v0 + v1*v1 + v2*v2 + v3*v3;
        vpp += __shfl_xor(vpp, 1);
        vpp += __shfl_xor(vpp, 2);
        const float vn2 = vpp + uv * uv;
        const float inv_vi = (vn2 > 0.0f) ? rsqrtf(vn2) : 0.0f;
        const long long base = (long long)cell * KP1_C;
        float maxq = -INFINITY;
        #pragma unroll
        for (int k = 1; k < KP1_C; ++k) {
            const int j = *(const int*)(idx_bytes + ((base + k) << shift));
            const float unj = unsplice[j];
            const float4 n4 = *(const float4*)(splices + (long long)j * N_ISO_C + 4 * q);
            const float d0 = n4.x - s4.x, d1 = n4.y - s4.y, d2 = n4.z - s4.z, d3 = n4.w - s4.w;
            float dp = v0*d0 + v1*d1 + v2*d2 + v3*d3;
            float np = d0*d0 + d1*d1 + d2*d2 + d3*d3;
            dp += __shfl_xor(dp, 1);  np += __shfl_xor(np, 1);
            dp += __shfl_xor(dp, 2);  np += __shfl_xor(np, 2);
            const float un  = unj - u_i;
            const float dot = dp + uv * un;
            const float nn2 = np + un * un;
            const float rn  = (nn2 > 0.0f) ? rsqrtf(nn2) : 0.0f;
            maxq = fmaxf(maxq, dot * rn);
        }
        if (q == 0) cost = 1.0f - maxq * inv_vi;
    }
    for (int off = 32; off > 0; off >>= 1) cost += __shfl_down(cost, off);
    __shared__ float wsum[BLOCK / 64];
    if ((tid & 63) == 0) wsum[tid >> 6] = cost;
    __syncthreads();
    if (tid == 0) {
        float s = 0.0f;
        #pragma unroll
        for (int wv = 0; wv < BLOCK / 64; ++wv) s += wsum[wv];
        partials[blockIdx.x] = s;
    }
}

__global__ __launch_bounds__(BLOCK) void final_reduce_kernel(
    const float* __restrict__ partials, int nparts, float* __restrict__ out)
{
    float s = 0.0f;
    for (int i = threadIdx.x; i < nparts; i += BLOCK) s += partials[i];
    for (int off = 32; off > 0; off >>= 1) s += __shfl_down(s, off);
    __shared__ float wsum[BLOCK / 64];
    if ((threadIdx.x & 63) == 0) wsum[threadIdx.x >> 6] = s;
    __syncthreads();
    if (threadIdx.x == 0) {
        float t = 0.0f;
        #pragma unroll
        for (int wv = 0; wv < BLOCK / 64; ++wv) t += wsum[wv];
        out[0] = t / (float)N_CELLS_C;
    }
}

extern "C" void kernel_launch(void* const* d_in, const int* in_sizes, int n_in,
                              void* d_out, int out_size, void* d_ws, size_t ws_size,
                              hipStream_t stream) {
    const float* unsplice         = (const float*)d_in[0];
    const float* splices          = (const float*)d_in[1];
    const float* unsplice_predict = (const float*)d_in[2];
    const float* splice_predicts  = (const float*)d_in[3];
    const char*  idx_bytes        = (const char*)d_in[4];
    float* out = (float*)d_out;

    // ws layout: [rec 3.2MB][partials]
    unsigned* rec      = (unsigned*)d_ws;
    float*    partials = (float*)((char*)d_ws + 3200000);

    const size_t req = 3200000 + 16 * 4096;

    if (ws_size >= req) {
        const int pack_blocks = (N_CELLS_C + BLOCK - 1) / BLOCK;      // 391
        pack_kernel<<<pack_blocks, BLOCK, 0, stream>>>(unsplice, splices, rec);
        const int nblocks = N_CELLS_C / (BLOCK / 8);                  // 3125, exact
        cost_kernel<<<nblocks, BLOCK, 0, stream>>>(
            unsplice, splices, unsplice_predict, splice_predicts,
            idx_bytes, rec, partials);
        final_reduce_kernel<<<1, BLOCK, 0, stream>>>(partials, nblocks, out);
    } else {
        float* fb_partials = (float*)d_ws;
        const int nblocks = (N_CELLS_C + (BLOCK / 4) - 1) / (BLOCK / 4);
        cost_kernel_f32<<<nblocks, BLOCK, 0, stream>>>(
            unsplice, splices, unsplice_predict, splice_predicts,
            idx_bytes, fb_partials);
        final_reduce_kernel<<<1, BLOCK, 0, stream>>>(fb_partials, nblocks, out);
    }
}